// Round 1
// baseline (210.995 us; speedup 1.0000x reference)
//
#include <hip/hip_runtime.h>
#include <hip/hip_bf16.h>
#include <stdint.h>

typedef __bf16 bf16_t;
typedef __bf16 bf16x8 __attribute__((ext_vector_type(8)));
typedef float  f32x4  __attribute__((ext_vector_type(4)));

#define T_LEN 2048
#define E_DIM 1024
#define H_NUM 16
#define D_DIM 64
#define LOG2E 1.44269504088896f

// async global->LDS, 16B per lane. LDS dest = wave-uniform base + lane*16.
__device__ __forceinline__ void gload_lds16(const void* g, void* l) {
    __builtin_amdgcn_global_load_lds(
        (__attribute__((address_space(1))) unsigned int*)(uintptr_t)g,
        (__attribute__((address_space(3))) unsigned int*)(uint32_t)(uintptr_t)l,
        16, 0, 0);
}

// ---------------- kernel 1: fp32 -> bf16 conversion / weight packing ----------
// embb: [4096][1024] bf16 ; wcat: [3072][1024] bf16 (rows 0-1023 Wq, 1024-2047 Wk, 2048-3071 Wv)
__global__ __launch_bounds__(256) void convert_kernel(
    const float* __restrict__ emb, const float* __restrict__ wq,
    const float* __restrict__ wk,  const float* __restrict__ wv,
    bf16_t* __restrict__ embb, bf16_t* __restrict__ wcat)
{
    size_t base = ((size_t)blockIdx.x * 256 + threadIdx.x) * 8;
    const float* src;
    bf16_t* dst;
    if (base < (size_t)4194304) { src = emb + base; dst = embb + base; }
    else {
        size_t r = base - 4194304;
        int wsel = (int)(r >> 20);
        size_t off = r & 1048575;
        src = (wsel == 0 ? wq : (wsel == 1 ? wk : wv)) + off;
        dst = wcat + r;
    }
    float4 a  = *(const float4*)src;
    float4 c2 = *(const float4*)(src + 4);
    bf16x8 o;
    o[0]=(bf16_t)a.x;  o[1]=(bf16_t)a.y;  o[2]=(bf16_t)a.z;  o[3]=(bf16_t)a.w;
    o[4]=(bf16_t)c2.x; o[5]=(bf16_t)c2.y; o[6]=(bf16_t)c2.z; o[7]=(bf16_t)c2.w;
    *(bf16x8*)dst = o;
}

// ---------------- kernel 2: QKV projection (NT GEMM, m97 structure) ----------
// C[4096][3072] = A[4096][1024] * Wc[3072][1024]^T
// q,k out: [B][H][T][D] bf16 ; vt out: [B][H][D][T] bf16 (transposed via LDS epilogue)
__global__ __launch_bounds__(256, 2) void proj_kernel(
    const bf16_t* __restrict__ A, const bf16_t* __restrict__ Wc,
    bf16_t* __restrict__ qo, bf16_t* __restrict__ ko, bf16_t* __restrict__ vto)
{
    __shared__ __align__(128) char smem[32768];
    bf16_t* As = (bf16_t*)smem;            // [128][32] bf16, 8KB
    bf16_t* Bs = (bf16_t*)(smem + 8192);   // [128][32] bf16, 8KB

    const int tid  = threadIdx.x;
    const int w    = tid >> 6, lane = tid & 63;
    const int wr   = w >> 1,  wc2  = w & 1;
    const int g    = lane >> 4, c = lane & 15;
    const int bm   = blockIdx.x & 31, bn = blockIdx.x >> 5;
    const int m0   = bm * 128, n0 = bn * 128;

    f32x4 acc[4][4] = {};

    const int arow = lane >> 2;          // 4 lanes per 64B row
    const int acol = (lane & 3) * 8;

    for (int kt = 0; kt < 32; ++kt) {
        __syncthreads();
        #pragma unroll
        for (int p = 0; p < 2; ++p) {
            gload_lds16(A  + (size_t)(m0 + p*64 + w*16 + arow) * 1024 + kt*32 + acol,
                        (char*)As + (p*64 + w*16) * 64);
            gload_lds16(Wc + (size_t)(n0 + p*64 + w*16 + arow) * 1024 + kt*32 + acol,
                        (char*)Bs + (p*64 + w*16) * 64);
        }
        __syncthreads();
        bf16x8 af[4], bf[4];
        #pragma unroll
        for (int i = 0; i < 4; ++i) {
            af[i] = *(const bf16x8*)(As + (wr*64  + i*16 + c) * 32 + g*8);
            bf[i] = *(const bf16x8*)(Bs + (wc2*64 + i*16 + c) * 32 + g*8);
        }
        #pragma unroll
        for (int i = 0; i < 4; ++i)
            #pragma unroll
            for (int j = 0; j < 4; ++j)
                acc[i][j] = __builtin_amdgcn_mfma_f32_16x16x32_bf16(af[i], bf[j], acc[i][j], 0, 0, 0);
    }

    const int b  = m0 >> 11;
    const int t0 = m0 & 2047;

    if (n0 < 2048) {
        // q or k: [b][h][t][d]
        bf16_t* dst = (n0 < 1024) ? qo : ko;
        const int nl0 = n0 & 1023;
        #pragma unroll
        for (int i = 0; i < 4; ++i) {
            #pragma unroll
            for (int j = 0; j < 4; ++j) {
                int nn = nl0 + wc2*64 + j*16 + c;
                int hh = nn >> 6, dd = nn & 63;
                size_t colbase = (size_t)(b*16 + hh) * 2048 * 64 + dd;
                #pragma unroll
                for (int e = 0; e < 4; ++e) {
                    int tt = t0 + wr*64 + i*16 + g*4 + e;
                    dst[colbase + (size_t)tt * 64] = (bf16_t)acc[i][j][e];
                }
            }
        }
    } else {
        // v: transpose 128x128 tile through LDS, store [b][h][d][t]
        __syncthreads();   // all waves done reading As/Bs
        #pragma unroll
        for (int i = 0; i < 4; ++i)
            #pragma unroll
            for (int j = 0; j < 4; ++j) {
                int dl = wc2*64 + j*16 + c;
                #pragma unroll
                for (int e = 0; e < 4; ++e) {
                    int tl = wr*64 + i*16 + g*4 + e;
                    *(bf16_t*)(smem + ((dl*256 + tl*2) ^ ((dl & 7) << 4))) = (bf16_t)acc[i][j][e];
                }
            }
        __syncthreads();
        const int nvbase = n0 - 2048;
        #pragma unroll
        for (int it = 0; it < 8; ++it) {
            int chunk = it * 256 + tid;      // 0..2047 16B-chunks
            int dl = chunk >> 4;
            int tc = (chunk & 15) * 8;
            bf16x8 val = *(const bf16x8*)(smem + ((dl*256 + tc*2) ^ ((dl & 7) << 4)));
            int nv = nvbase + dl;
            int hh = nv >> 6, dd = nv & 63;
            *(bf16x8*)(vto + (size_t)((b*16 + hh)*64 + dd) * 2048 + t0 + tc) = val;
        }
    }
}

// ---------------- kernel 3: causal flash attention -----------------------------
// q,k: [BH][T][D] bf16 ; vt: [BH][D][T] bf16 ; out: [B][T][H*D] fp32
// grid 256: (bh, pair p) ; passes qt = p then 15-p (load-balanced).
__global__ __launch_bounds__(256, 2) void attn_kernel(
    const bf16_t* __restrict__ qg, const bf16_t* __restrict__ kg,
    const bf16_t* __restrict__ vtg, float* __restrict__ out)
{
    __shared__ __align__(128) char smem[32768];
    char* Ks = smem;            // 8KB  [64 t][64 d] xor-swizzled
    char* Vs = smem + 8192;     // 8KB  [64 d][64 t] xor-swizzled
    char* Ps = smem + 16384;    // 16KB [128 q][64 k] xor-swizzled

    const int tid = threadIdx.x;
    const int w = tid >> 6, lane = tid & 63;
    const int g = lane >> 4, c = lane & 15;
    const int bh = blockIdx.x >> 3, pp = blockIdx.x & 7;
    const int b = bh >> 4, h = bh & 15;

    const bf16_t* qbase = qg  + (size_t)bh * T_LEN * D_DIM;
    const bf16_t* kbase = kg  + (size_t)bh * T_LEN * D_DIM;
    const bf16_t* vbase = vtg + (size_t)bh * D_DIM * T_LEN;
    float* obase = out + (size_t)b * T_LEN * 1024 + h * 64;

    const int srow = lane >> 3;                 // 0..7 (row within 8-row chunk)
    const int scol = ((lane & 7) ^ srow) * 8;   // pre-swizzled source column

    for (int pass = 0; pass < 2; ++pass) {
        const int qt = pass ? (15 - pp) : pp;
        const int q0 = qt * 128;

        // Q fragments in registers, pre-scaled by 1/sqrt(D)=0.125 (exact)
        bf16x8 qf[2][2];
        #pragma unroll
        for (int mi = 0; mi < 2; ++mi)
            #pragma unroll
            for (int kf = 0; kf < 2; ++kf) {
                bf16x8 v = *(const bf16x8*)(qbase + (size_t)(q0 + w*32 + mi*16 + c) * 64 + kf*32 + g*8);
                #pragma unroll
                for (int e = 0; e < 8; ++e) qf[mi][kf][e] = (bf16_t)((float)v[e] * 0.125f);
            }

        f32x4 oacc[2][4] = {};
        float mrun[2][4], lrun[2][4];
        #pragma unroll
        for (int mi = 0; mi < 2; ++mi)
            #pragma unroll
            for (int e = 0; e < 4; ++e) { mrun[mi][e] = -INFINITY; lrun[mi][e] = 0.0f; }

        const int nt = 2*qt + 2;
        for (int kt = 0; kt < nt; ++kt) {
            __syncthreads();
            #pragma unroll
            for (int p2 = 0; p2 < 2; ++p2) {
                int ch = p2*4 + w;
                int r  = ch*8 + srow;
                gload_lds16(kbase + (size_t)(kt*64 + r) * 64 + scol, Ks + ch*1024);
                gload_lds16(vbase + (size_t)r * 2048 + kt*64 + scol, Vs + ch*1024);
            }
            __syncthreads();

            // S = Q K^T  (NT: both frags are row-slices)
            bf16x8 kfr[4][2];
            #pragma unroll
            for (int ni = 0; ni < 4; ++ni)
                #pragma unroll
                for (int kf = 0; kf < 2; ++kf)
                    kfr[ni][kf] = *(const bf16x8*)(Ks + (((ni*16 + c)*128 + kf*64 + g*16) ^ ((c & 7) << 4)));
            f32x4 sacc[2][4];
            #pragma unroll
            for (int mi = 0; mi < 2; ++mi)
                #pragma unroll
                for (int ni = 0; ni < 4; ++ni) {
                    f32x4 s0 = {0.f, 0.f, 0.f, 0.f};
                    s0 = __builtin_amdgcn_mfma_f32_16x16x32_bf16(qf[mi][0], kfr[ni][0], s0, 0, 0, 0);
                    s0 = __builtin_amdgcn_mfma_f32_16x16x32_bf16(qf[mi][1], kfr[ni][1], s0, 0, 0, 0);
                    sacc[mi][ni] = s0;
                }

            if (kt >= 2*qt) {   // diagonal tiles: causal mask
                #pragma unroll
                for (int mi = 0; mi < 2; ++mi)
                    #pragma unroll
                    for (int ni = 0; ni < 4; ++ni)
                        #pragma unroll
                        for (int e = 0; e < 4; ++e) {
                            int kk = kt*64 + ni*16 + c;
                            int qq = q0 + w*32 + mi*16 + g*4 + e;
                            if (kk > qq) sacc[mi][ni][e] = -INFINITY;
                        }
            }

            // online softmax (rows live in 16-lane c-groups)
            float sf[2][4];
            #pragma unroll
            for (int mi = 0; mi < 2; ++mi)
                #pragma unroll
                for (int e = 0; e < 4; ++e) {
                    float mx = fmaxf(fmaxf(sacc[mi][0][e], sacc[mi][1][e]),
                                     fmaxf(sacc[mi][2][e], sacc[mi][3][e]));
                    mx = fmaxf(mx, __shfl_xor(mx, 1));
                    mx = fmaxf(mx, __shfl_xor(mx, 2));
                    mx = fmaxf(mx, __shfl_xor(mx, 4));
                    mx = fmaxf(mx, __shfl_xor(mx, 8));
                    float mnew  = fmaxf(mrun[mi][e], mx);
                    float scale = exp2f((mrun[mi][e] - mnew) * LOG2E);
                    float ps = 0.f;
                    #pragma unroll
                    for (int ni = 0; ni < 4; ++ni) {
                        float pv = exp2f((sacc[mi][ni][e] - mnew) * LOG2E);
                        sacc[mi][ni][e] = pv;   // reuse regs as P
                        ps += pv;
                    }
                    ps += __shfl_xor(ps, 1);
                    ps += __shfl_xor(ps, 2);
                    ps += __shfl_xor(ps, 4);
                    ps += __shfl_xor(ps, 8);
                    lrun[mi][e] = lrun[mi][e] * scale + ps;
                    mrun[mi][e] = mnew;
                    sf[mi][e]   = scale;
                }

            #pragma unroll
            for (int mi = 0; mi < 2; ++mi)
                #pragma unroll
                for (int db = 0; db < 4; ++db)
                    #pragma unroll
                    for (int e = 0; e < 4; ++e)
                        oacc[mi][db][e] *= sf[mi][e];

            // P -> LDS (bf16, swizzled); per-wave region only, same-wave RAW
            #pragma unroll
            for (int mi = 0; mi < 2; ++mi)
                #pragma unroll
                for (int ni = 0; ni < 4; ++ni)
                    #pragma unroll
                    for (int e = 0; e < 4; ++e) {
                        int row = w*32 + mi*16 + g*4 + e;
                        *(bf16_t*)(Ps + ((row*128 + (ni*16 + c)*2) ^ ((row & 7) << 4))) =
                            (bf16_t)sacc[mi][ni][e];
                    }

            // O += P V
            bf16x8 vfr[4][2];
            #pragma unroll
            for (int db = 0; db < 4; ++db)
                #pragma unroll
                for (int kf = 0; kf < 2; ++kf)
                    vfr[db][kf] = *(const bf16x8*)(Vs + (((db*16 + c)*128 + kf*64 + g*16) ^ ((c & 7) << 4)));
            bf16x8 pfr[2][2];
            #pragma unroll
            for (int mi = 0; mi < 2; ++mi)
                #pragma unroll
                for (int kf = 0; kf < 2; ++kf) {
                    int row = w*32 + mi*16 + c;
                    pfr[mi][kf] = *(const bf16x8*)(Ps + ((row*128 + kf*64 + g*16) ^ ((row & 7) << 4)));
                }
            #pragma unroll
            for (int mi = 0; mi < 2; ++mi)
                #pragma unroll
                for (int db = 0; db < 4; ++db) {
                    oacc[mi][db] = __builtin_amdgcn_mfma_f32_16x16x32_bf16(pfr[mi][0], vfr[db][0], oacc[mi][db], 0, 0, 0);
                    oacc[mi][db] = __builtin_amdgcn_mfma_f32_16x16x32_bf16(pfr[mi][1], vfr[db][1], oacc[mi][db], 0, 0, 0);
                }
        }

        // epilogue: normalize + fp32 store to [b][t][h*64+d]
        #pragma unroll
        for (int mi = 0; mi < 2; ++mi)
            #pragma unroll
            for (int e = 0; e < 4; ++e) {
                float inv = 1.0f / lrun[mi][e];
                size_t trow = (size_t)(q0 + w*32 + mi*16 + g*4 + e);
                #pragma unroll
                for (int db = 0; db < 4; ++db)
                    obase[trow * 1024 + db*16 + c] = oacc[mi][db][e] * inv;
            }
    }
}

extern "C" void kernel_launch(void* const* d_in, const int* in_sizes, int n_in,
                              void* d_out, int out_size, void* d_ws, size_t ws_size,
                              hipStream_t stream) {
    const float* emb = (const float*)d_in[0];
    const float* wq  = (const float*)d_in[1];
    const float* wk  = (const float*)d_in[2];
    const float* wv  = (const float*)d_in[3];
    float* out = (float*)d_out;

    char* ws = (char*)d_ws;
    bf16_t* embb = (bf16_t*)ws;                          // 8 MB  [4096][1024]
    bf16_t* wcat = (bf16_t*)(ws + (size_t) 8*1024*1024); // 6 MB  [3072][1024]
    bf16_t* qb   = (bf16_t*)(ws + (size_t)14*1024*1024); // 8 MB  [BH][T][D]
    bf16_t* kb   = (bf16_t*)(ws + (size_t)22*1024*1024); // 8 MB  [BH][T][D]
    bf16_t* vtb  = (bf16_t*)(ws + (size_t)30*1024*1024); // 8 MB  [BH][D][T]

    convert_kernel<<<3584, 256, 0, stream>>>(emb, wq, wk, wv, embb, wcat);
    proj_kernel<<<768, 256, 0, stream>>>(embb, wcat, qb, kb, vtb);
    attn_kernel<<<256, 256, 0, stream>>>(qb, kb, vtb, out);
}

// Round 2
// 180.816 us; speedup vs baseline: 1.1669x; 1.1669x over previous
//
#include <hip/hip_runtime.h>
#include <hip/hip_bf16.h>
#include <stdint.h>

typedef __bf16 bf16_t;
typedef __bf16 bf16x8 __attribute__((ext_vector_type(8)));
typedef float  f32x4  __attribute__((ext_vector_type(4)));

#define LOG2E 1.44269504088896f

// async global->LDS, 16B per lane. LDS dest must be wave-uniform base (+lane*16 by HW).
__device__ __forceinline__ void gload_lds16(const void* g, void* l) {
    __builtin_amdgcn_global_load_lds(
        (__attribute__((address_space(1))) unsigned int*)(uintptr_t)g,
        (__attribute__((address_space(3))) unsigned int*)(uint32_t)(uintptr_t)l,
        16, 0, 0);
}

// ---------------- kernel 1: fp32 -> bf16 conversion / weight packing ----------
__global__ __launch_bounds__(256) void convert_kernel(
    const float* __restrict__ emb, const float* __restrict__ wq,
    const float* __restrict__ wk,  const float* __restrict__ wv,
    bf16_t* __restrict__ embb, bf16_t* __restrict__ wcat)
{
    size_t base = ((size_t)blockIdx.x * 256 + threadIdx.x) * 8;
    const float* src;
    bf16_t* dst;
    if (base < (size_t)4194304) { src = emb + base; dst = embb + base; }
    else {
        size_t r = base - 4194304;
        int wsel = (int)(r >> 20);
        size_t off = r & 1048575;
        src = (wsel == 0 ? wq : (wsel == 1 ? wk : wv)) + off;
        dst = wcat + r;
    }
    float4 a  = *(const float4*)src;
    float4 c2 = *(const float4*)(src + 4);
    bf16x8 o;
    o[0]=(bf16_t)a.x;  o[1]=(bf16_t)a.y;  o[2]=(bf16_t)a.z;  o[3]=(bf16_t)a.w;
    o[4]=(bf16_t)c2.x; o[5]=(bf16_t)c2.y; o[6]=(bf16_t)c2.z; o[7]=(bf16_t)c2.w;
    *(bf16x8*)dst = o;
}

// ---------------- kernel 2: QKV projection (NT GEMM, dbuf, swizzled LDS) ------
// C[4096][3072] = A[4096][1024] * Wc[3072][1024]^T
// q,k out: [B][H][T][D] bf16 ; vt out: [B][H][D][T] bf16
__global__ __launch_bounds__(256, 3) void proj_kernel(
    const bf16_t* __restrict__ A, const bf16_t* __restrict__ Wc,
    bf16_t* __restrict__ qo, bf16_t* __restrict__ ko, bf16_t* __restrict__ vto)
{
    __shared__ __align__(128) char smem[32768];
    // dbuf: buf b -> As at smem+b*16384 ([128 rows][64B], slot-swizzled), Bs at +8192

    const int tid  = threadIdx.x;
    const int w    = tid >> 6, lane = tid & 63;
    const int wr   = w >> 1,  wc2  = w & 1;
    const int g    = lane >> 4, c = lane & 15;
    const int bm   = blockIdx.x & 31, bn = blockIdx.x >> 5;
    const int m0   = bm * 128, n0 = bn * 128;

    f32x4 acc[4][4] = {};

    const int arow = lane >> 2;                              // 4 lanes per 64B row
    const int acol = (((lane & 3) ^ ((lane >> 3) & 3))) * 8; // pre-swizzled source slot

    // stage K-step kt into buffer buf (linear LDS dest, swizzled global source)
    #define PROJ_STAGE(buf, kt)                                                        \
        do {                                                                           \
            char* As_ = smem + (buf) * 16384;                                          \
            char* Bs_ = As_ + 8192;                                                    \
            _Pragma("unroll")                                                          \
            for (int p = 0; p < 2; ++p) {                                              \
                gload_lds16(A  + (size_t)(m0 + p*64 + w*16 + arow) * 1024 + (kt)*32 + acol, \
                            As_ + (p*64 + w*16) * 64);                                 \
                gload_lds16(Wc + (size_t)(n0 + p*64 + w*16 + arow) * 1024 + (kt)*32 + acol, \
                            Bs_ + (p*64 + w*16) * 64);                                 \
            }                                                                          \
        } while (0)

    PROJ_STAGE(0, 0);
    __syncthreads();
    int cur = 0;
    for (int kt = 0; kt < 32; ++kt) {
        if (kt < 31) PROJ_STAGE(cur ^ 1, kt + 1);
        const char* As = smem + cur * 16384;
        const char* Bs = As + 8192;
        const int sw = (c >> 1) & 3;  // row-slot swizzle key
        bf16x8 af[4], bf[4];
        #pragma unroll
        for (int i = 0; i < 4; ++i) {
            af[i] = *(const bf16x8*)(As + (wr*64  + i*16 + c) * 64 + ((g ^ sw) << 4));
            bf[i] = *(const bf16x8*)(Bs + (wc2*64 + i*16 + c) * 64 + ((g ^ sw) << 4));
        }
        #pragma unroll
        for (int i = 0; i < 4; ++i)
            #pragma unroll
            for (int j = 0; j < 4; ++j)
                acc[i][j] = __builtin_amdgcn_mfma_f32_16x16x32_bf16(af[i], bf[j], acc[i][j], 0, 0, 0);
        __syncthreads();
        cur ^= 1;
    }

    const int b  = m0 >> 11;
    const int t0 = m0 & 2047;

    if (n0 < 2048) {
        // q or k: transpose-free orientation [t][n] in LDS, store 16B rows of [b][h][t][d]
        bf16_t* dst = (n0 < 1024) ? qo : ko;
        const int nl0 = n0 & 1023;
        #pragma unroll
        for (int i = 0; i < 4; ++i)
            #pragma unroll
            for (int j = 0; j < 4; ++j) {
                int dl = wc2*64 + j*16 + c;
                #pragma unroll
                for (int e = 0; e < 4; ++e) {
                    int tl = wr*64 + i*16 + g*4 + e;
                    *(bf16_t*)(smem + ((tl*256 + dl*2) ^ ((tl & 7) << 4))) = (bf16_t)acc[i][j][e];
                }
            }
        __syncthreads();
        #pragma unroll
        for (int it = 0; it < 8; ++it) {
            int chunk = it * 256 + tid;          // 2048 x 16B chunks
            int tl = chunk >> 4;
            int ce = (chunk & 15) * 8;
            bf16x8 val = *(const bf16x8*)(smem + ((tl*256 + ce*2) ^ ((tl & 7) << 4)));
            int nn = nl0 + ce;
            int hh = nn >> 6, dd = nn & 63;
            *(bf16x8*)(dst + ((size_t)(b*16 + hh) * 2048 + (t0 + tl)) * 64 + dd) = val;
        }
    } else {
        // v: [n][t] in LDS, store 16B rows of [b][h][d][t]
        #pragma unroll
        for (int i = 0; i < 4; ++i)
            #pragma unroll
            for (int j = 0; j < 4; ++j) {
                int dl = wc2*64 + j*16 + c;
                #pragma unroll
                for (int e = 0; e < 4; ++e) {
                    int tl = wr*64 + i*16 + g*4 + e;
                    *(bf16_t*)(smem + ((dl*256 + tl*2) ^ ((dl & 7) << 4))) = (bf16_t)acc[i][j][e];
                }
            }
        __syncthreads();
        const int nvbase = n0 - 2048;
        #pragma unroll
        for (int it = 0; it < 8; ++it) {
            int chunk = it * 256 + tid;
            int dl = chunk >> 4;
            int tc = (chunk & 15) * 8;
            bf16x8 val = *(const bf16x8*)(smem + ((dl*256 + tc*2) ^ ((dl & 7) << 4)));
            int nv = nvbase + dl;
            int hh = nv >> 6, dd = nv & 63;
            *(bf16x8*)(vto + (size_t)((b*16 + hh)*64 + dd) * 2048 + t0 + tc) = val;
        }
    }
    #undef PROJ_STAGE
}

// ---------------- kernel 3: causal flash attention (8 waves, dbuf pipeline) ----
// q,k: [BH][T][D] bf16 ; vt: [BH][D][T] bf16 ; out: [B][T][H*D] fp32
// grid 512: one (bh, qt) per block, heavy qt first for load balance.
__global__ __launch_bounds__(512, 4) void attn_kernel(
    const bf16_t* __restrict__ qg, const bf16_t* __restrict__ kg,
    const bf16_t* __restrict__ vtg, float* __restrict__ out)
{
    __shared__ __align__(128) char smem[49152];
    // buf b: K at smem+b*16384 (8KB, [64 t][64 d] swz), V at +8192 ([64 d][64 t] swz)
    char* Ps = smem + 32768;    // 16KB [128 q][64 k] swizzled

    const int tid = threadIdx.x;
    const int w = tid >> 6, lane = tid & 63;   // w in 0..7
    const int g = lane >> 4, c = lane & 15;
    const int id = blockIdx.x;
    const int qt = 15 - (id >> 5);             // heavy first
    const int bh = id & 31;
    const int b = bh >> 4, h = bh & 15;

    const bf16_t* qbase = qg  + (size_t)bh * 2048 * 64;
    const bf16_t* kbase = kg  + (size_t)bh * 2048 * 64;
    const bf16_t* vbase = vtg + (size_t)bh * 64 * 2048;
    float* obase = out + (size_t)b * 2048 * 1024 + h * 64;

    const int srow = lane >> 3;                 // row within 8-row chunk
    const int scol = ((lane & 7) ^ srow) * 8;   // pre-swizzled source column

    const int q0 = qt * 128;
    const int nt = 2 * qt + 2;

    // Q fragments (wave owns rows q0+w*16 .. +15), pre-scaled by 1/sqrt(64)
    bf16x8 qf[2];
    #pragma unroll
    for (int kf = 0; kf < 2; ++kf) {
        bf16x8 v = *(const bf16x8*)(qbase + (size_t)(q0 + w*16 + c) * 64 + kf*32 + g*8);
        #pragma unroll
        for (int e = 0; e < 8; ++e) qf[kf][e] = (bf16_t)((float)v[e] * 0.125f);
    }

    f32x4 oacc[4] = {};
    float mrun[4], lrun[4];
    #pragma unroll
    for (int e = 0; e < 4; ++e) { mrun[e] = -INFINITY; lrun[e] = 0.0f; }

    // each wave stages one 1KB chunk of K and one of V (8 rows each)
    #define ATTN_STAGE(buf, kt)                                                         \
        do {                                                                            \
            char* Kb_ = smem + (buf) * 16384;                                           \
            gload_lds16(kbase + (size_t)((kt)*64 + w*8 + srow) * 64 + scol, Kb_ + w*1024); \
            gload_lds16(vbase + (size_t)(w*8 + srow) * 2048 + (kt)*64 + scol,           \
                        Kb_ + 8192 + w*1024);                                           \
        } while (0)

    ATTN_STAGE(0, 0);
    __syncthreads();
    int cur = 0;

    for (int kt = 0; kt < nt; ++kt) {
        if (kt + 1 < nt) ATTN_STAGE(cur ^ 1, kt + 1);
        const char* Kb = smem + cur * 16384;
        const char* Vb = Kb + 8192;

        // S = Q K^T
        f32x4 sacc[4];
        #pragma unroll
        for (int ni = 0; ni < 4; ++ni) {
            int krow = ni*16 + c;
            bf16x8 k0 = *(const bf16x8*)(Kb + ((krow*128 +      g*16) ^ ((c & 7) << 4)));
            bf16x8 k1 = *(const bf16x8*)(Kb + ((krow*128 + 64 + g*16) ^ ((c & 7) << 4)));
            f32x4 s0 = {0.f, 0.f, 0.f, 0.f};
            s0 = __builtin_amdgcn_mfma_f32_16x16x32_bf16(qf[0], k0, s0, 0, 0, 0);
            s0 = __builtin_amdgcn_mfma_f32_16x16x32_bf16(qf[1], k1, s0, 0, 0, 0);
            sacc[ni] = s0;
        }

        if (kt >= 2*qt) {   // diagonal tiles: causal mask
            #pragma unroll
            for (int ni = 0; ni < 4; ++ni)
                #pragma unroll
                for (int e = 0; e < 4; ++e) {
                    int kk = kt*64 + ni*16 + c;
                    int qq = q0 + w*16 + g*4 + e;
                    if (kk > qq) sacc[ni][e] = -INFINITY;
                }
        }

        // online softmax (row = 16-lane c-group per (g,e))
        float sf[4];
        #pragma unroll
        for (int e = 0; e < 4; ++e) {
            float mx = fmaxf(fmaxf(sacc[0][e], sacc[1][e]),
                             fmaxf(sacc[2][e], sacc[3][e]));
            mx = fmaxf(mx, __shfl_xor(mx, 1));
            mx = fmaxf(mx, __shfl_xor(mx, 2));
            mx = fmaxf(mx, __shfl_xor(mx, 4));
            mx = fmaxf(mx, __shfl_xor(mx, 8));
            float mnew  = fmaxf(mrun[e], mx);
            float scale = exp2f((mrun[e] - mnew) * LOG2E);
            float ps = 0.f;
            #pragma unroll
            for (int ni = 0; ni < 4; ++ni) {
                float pv = exp2f((sacc[ni][e] - mnew) * LOG2E);
                sacc[ni][e] = pv;
                ps += pv;
            }
            ps += __shfl_xor(ps, 1);
            ps += __shfl_xor(ps, 2);
            ps += __shfl_xor(ps, 4);
            ps += __shfl_xor(ps, 8);
            lrun[e] = lrun[e] * scale + ps;
            mrun[e] = mnew;
            sf[e]   = scale;
        }
        #pragma unroll
        for (int db = 0; db < 4; ++db)
            #pragma unroll
            for (int e = 0; e < 4; ++e)
                oacc[db][e] *= sf[e];

        // P -> LDS (own rows only; same-wave RAW)
        #pragma unroll
        for (int ni = 0; ni < 4; ++ni)
            #pragma unroll
            for (int e = 0; e < 4; ++e) {
                int row = w*16 + g*4 + e;
                *(bf16_t*)(Ps + ((row*128 + (ni*16 + c)*2) ^ ((row & 7) << 4))) =
                    (bf16_t)sacc[ni][e];
            }

        // O += P V
        bf16x8 pfr[2];
        {
            int prow = w*16 + c;
            pfr[0] = *(const bf16x8*)(Ps + ((prow*128 +      g*16) ^ ((prow & 7) << 4)));
            pfr[1] = *(const bf16x8*)(Ps + ((prow*128 + 64 + g*16) ^ ((prow & 7) << 4)));
        }
        #pragma unroll
        for (int db = 0; db < 4; ++db) {
            int vrow = db*16 + c;
            bf16x8 v0 = *(const bf16x8*)(Vb + ((vrow*128 +      g*16) ^ ((c & 7) << 4)));
            bf16x8 v1 = *(const bf16x8*)(Vb + ((vrow*128 + 64 + g*16) ^ ((c & 7) << 4)));
            oacc[db] = __builtin_amdgcn_mfma_f32_16x16x32_bf16(pfr[0], v0, oacc[db], 0, 0, 0);
            oacc[db] = __builtin_amdgcn_mfma_f32_16x16x32_bf16(pfr[1], v1, oacc[db], 0, 0, 0);
        }

        __syncthreads();   // staged buf ready (drains vmcnt) + all waves done with Kb/Vb
        cur ^= 1;
    }

    // epilogue: normalize + fp32 store [b][t][h*64+d]
    #pragma unroll
    for (int e = 0; e < 4; ++e) {
        float inv = 1.0f / lrun[e];
        size_t trow = (size_t)(q0 + w*16 + g*4 + e);
        #pragma unroll
        for (int db = 0; db < 4; ++db)
            obase[trow * 1024 + db*16 + c] = oacc[db][e] * inv;
    }
    #undef ATTN_STAGE
}

extern "C" void kernel_launch(void* const* d_in, const int* in_sizes, int n_in,
                              void* d_out, int out_size, void* d_ws, size_t ws_size,
                              hipStream_t stream) {
    const float* emb = (const float*)d_in[0];
    const float* wq  = (const float*)d_in[1];
    const float* wk  = (const float*)d_in[2];
    const float* wv  = (const float*)d_in[3];
    float* out = (float*)d_out;

    char* ws = (char*)d_ws;
    bf16_t* embb = (bf16_t*)ws;                          // 8 MB  [4096][1024]
    bf16_t* wcat = (bf16_t*)(ws + (size_t) 8*1024*1024); // 6 MB  [3072][1024]
    bf16_t* qb   = (bf16_t*)(ws + (size_t)14*1024*1024); // 8 MB  [BH][T][D]
    bf16_t* kb   = (bf16_t*)(ws + (size_t)22*1024*1024); // 8 MB  [BH][T][D]
    bf16_t* vtb  = (bf16_t*)(ws + (size_t)30*1024*1024); // 8 MB  [BH][D][T]

    convert_kernel<<<3584, 256, 0, stream>>>(emb, wq, wk, wv, embb, wcat);
    proj_kernel<<<768, 256, 0, stream>>>(embb, wcat, qb, kb, vtb);
    attn_kernel<<<512, 512, 0, stream>>>(qb, kb, vtb, out);
}

// Round 4
// 154.443 us; speedup vs baseline: 1.3662x; 1.1708x over previous
//
#include <hip/hip_runtime.h>
#include <hip/hip_bf16.h>
#include <stdint.h>

typedef __bf16 bf16_t;
typedef __bf16 bf16x4 __attribute__((ext_vector_type(4)));
typedef __bf16 bf16x8 __attribute__((ext_vector_type(8)));
typedef float  f32x4  __attribute__((ext_vector_type(4)));

#define QK_SCALE 0.1803368801111204f   /* 0.125 * log2(e): softmax runs in log2 domain */

// async global->LDS, 16B per lane. LDS dest must be wave-uniform base (+lane*16 by HW).
__device__ __forceinline__ void gload_lds16(const void* g, void* l) {
    __builtin_amdgcn_global_load_lds(
        (__attribute__((address_space(1))) unsigned int*)(uintptr_t)g,
        (__attribute__((address_space(3))) unsigned int*)(uint32_t)(uintptr_t)l,
        16, 0, 0);
}

// ---------------- kernel 1: fp32 -> bf16 conversion / weight packing ----------
__global__ __launch_bounds__(256) void convert_kernel(
    const float* __restrict__ emb, const float* __restrict__ wq,
    const float* __restrict__ wk,  const float* __restrict__ wv,
    bf16_t* __restrict__ embb, bf16_t* __restrict__ wcat)
{
    size_t base = ((size_t)blockIdx.x * 256 + threadIdx.x) * 8;
    const float* src;
    bf16_t* dst;
    if (base < (size_t)4194304) { src = emb + base; dst = embb + base; }
    else {
        size_t r = base - 4194304;
        int wsel = (int)(r >> 20);
        size_t off = r & 1048575;
        src = (wsel == 0 ? wq : (wsel == 1 ? wk : wv)) + off;
        dst = wcat + r;
    }
    float4 a  = *(const float4*)src;
    float4 c2 = *(const float4*)(src + 4);
    bf16x8 o;
    o[0]=(bf16_t)a.x;  o[1]=(bf16_t)a.y;  o[2]=(bf16_t)a.z;  o[3]=(bf16_t)a.w;
    o[4]=(bf16_t)c2.x; o[5]=(bf16_t)c2.y; o[6]=(bf16_t)c2.z; o[7]=(bf16_t)c2.w;
    *(bf16x8*)dst = o;
}

// ---------------- kernel 2: QKV projection (NT GEMM, 3-buf counted-vmcnt) -----
// C[4096][3072] = A[4096][1024] * Wc[3072][1024]^T
__global__ __launch_bounds__(256, 3) void proj_kernel(
    const bf16_t* __restrict__ A, const bf16_t* __restrict__ Wc,
    bf16_t* __restrict__ qo, bf16_t* __restrict__ ko, bf16_t* __restrict__ vto)
{
    __shared__ __align__(128) char smem[49152];
    // buf i at smem+i*16384: As [128 rows][64B] slot-swizzled, Bs at +8192

    const int tid  = threadIdx.x;
    const int w    = tid >> 6, lane = tid & 63;
    const int wr   = w >> 1,  wc2  = w & 1;
    const int g    = lane >> 4, c = lane & 15;
    const int bm   = blockIdx.x & 31, bn = blockIdx.x >> 5;
    const int m0   = bm * 128, n0 = bn * 128;

    f32x4 acc[4][4] = {};

    const int arow = lane >> 2;                              // 4 lanes per 64B row
    const int acol = (((lane & 3) ^ ((lane >> 3) & 3))) * 8; // pre-swizzled source slot

    #define PROJ_STAGE(buf, kt)                                                        \
        do {                                                                           \
            char* As_ = smem + (buf) * 16384;                                          \
            char* Bs_ = As_ + 8192;                                                    \
            _Pragma("unroll")                                                          \
            for (int p = 0; p < 2; ++p) {                                              \
                gload_lds16(A  + (size_t)(m0 + p*64 + w*16 + arow) * 1024 + (kt)*32 + acol, \
                            As_ + (p*64 + w*16) * 64);                                 \
                gload_lds16(Wc + (size_t)(n0 + p*64 + w*16 + arow) * 1024 + (kt)*32 + acol, \
                            Bs_ + (p*64 + w*16) * 64);                                 \
            }                                                                          \
        } while (0)

    PROJ_STAGE(0, 0);
    PROJ_STAGE(1, 1);
    int cur = 0;
    for (int kt = 0; kt < 32; ++kt) {
        if (kt == 31) asm volatile("s_waitcnt vmcnt(0)" ::: "memory");
        else          asm volatile("s_waitcnt vmcnt(4)" ::: "memory");
        __builtin_amdgcn_s_barrier();
        asm volatile("" ::: "memory");
        if (kt + 2 < 32) {
            int b2 = cur + 2; if (b2 >= 3) b2 -= 3;
            PROJ_STAGE(b2, kt + 2);
        }
        const char* As = smem + cur * 16384;
        const char* Bs = As + 8192;
        const int sw = (c >> 1) & 3;  // row-slot swizzle key
        bf16x8 af[4], bf[4];
        #pragma unroll
        for (int i = 0; i < 4; ++i) {
            af[i] = *(const bf16x8*)(As + (wr*64  + i*16 + c) * 64 + ((g ^ sw) << 4));
            bf[i] = *(const bf16x8*)(Bs + (wc2*64 + i*16 + c) * 64 + ((g ^ sw) << 4));
        }
        #pragma unroll
        for (int i = 0; i < 4; ++i)
            #pragma unroll
            for (int j = 0; j < 4; ++j)
                acc[i][j] = __builtin_amdgcn_mfma_f32_16x16x32_bf16(af[i], bf[j], acc[i][j], 0, 0, 0);
        cur = (cur == 2) ? 0 : cur + 1;
    }
    __syncthreads();   // all waves done with LDS bufs before epilogue reuses smem

    const int b  = m0 >> 11;
    const int t0 = m0 & 2047;

    if (n0 < 2048) {
        // q or k: [t][n] orientation in LDS, 16B-row stores of [b][h][t][d]
        bf16_t* dst = (n0 < 1024) ? qo : ko;
        const int nl0 = n0 & 1023;
        #pragma unroll
        for (int i = 0; i < 4; ++i)
            #pragma unroll
            for (int j = 0; j < 4; ++j) {
                int dl = wc2*64 + j*16 + c;
                #pragma unroll
                for (int e = 0; e < 4; ++e) {
                    int tl = wr*64 + i*16 + g*4 + e;
                    *(bf16_t*)(smem + ((tl*256 + dl*2) ^ ((tl & 7) << 4))) = (bf16_t)acc[i][j][e];
                }
            }
        __syncthreads();
        #pragma unroll
        for (int it = 0; it < 8; ++it) {
            int chunk = it * 256 + tid;          // 2048 x 16B chunks
            int tl = chunk >> 4;
            int ce = (chunk & 15) * 8;
            bf16x8 val = *(const bf16x8*)(smem + ((tl*256 + ce*2) ^ ((tl & 7) << 4)));
            int nn = nl0 + ce;
            int hh = nn >> 6, dd = nn & 63;
            *(bf16x8*)(dst + ((size_t)(b*16 + hh) * 2048 + (t0 + tl)) * 64 + dd) = val;
        }
    } else {
        // v: [n][t] orientation in LDS, 16B-row stores of [b][h][d][t]
        #pragma unroll
        for (int i = 0; i < 4; ++i)
            #pragma unroll
            for (int j = 0; j < 4; ++j) {
                int dl = wc2*64 + j*16 + c;
                #pragma unroll
                for (int e = 0; e < 4; ++e) {
                    int tl = wr*64 + i*16 + g*4 + e;
                    *(bf16_t*)(smem + ((dl*256 + tl*2) ^ ((dl & 7) << 4))) = (bf16_t)acc[i][j][e];
                }
            }
        __syncthreads();
        const int nvbase = n0 - 2048;
        #pragma unroll
        for (int it = 0; it < 8; ++it) {
            int chunk = it * 256 + tid;
            int dl = chunk >> 4;
            int tc = (chunk & 15) * 8;
            bf16x8 val = *(const bf16x8*)(smem + ((dl*256 + tc*2) ^ ((dl & 7) << 4)));
            int nv = nvbase + dl;
            int hh = nv >> 6, dd = nv & 63;
            *(bf16x8*)(vto + (size_t)((b*16 + hh)*64 + dd) * 2048 + t0 + tc) = val;
        }
    }
    #undef PROJ_STAGE
}

// ---------------- kernel 3: causal flash attention ----------------------------
// Swapped QK^T (mfma(K,Q)) -> lane-local softmax rows; P stays in registers and
// feeds PV 16x16x32 via ni-block concatenation (k = ni*16+g*4+e bijection).
// 4 waves x 16 q-rows (QBLK=64); 3-buf K/V staging, counted vmcnt.
// grid 1024: id -> (qt heavy-first, bh in low bits for XCD L2 locality)
__global__ __launch_bounds__(256, 3) void attn_kernel(
    const bf16_t* __restrict__ qg, const bf16_t* __restrict__ kg,
    const bf16_t* __restrict__ vtg, float* __restrict__ out)
{
    __shared__ __align__(128) char smem[49152];
    // buf i at smem+i*16384: Ks [64 t][64 d] swz (8KB), Vs [64 d][64 t] swz (8KB)

    const int tid = threadIdx.x;
    const int w = tid >> 6, lane = tid & 63;   // 4 waves
    const int g = lane >> 4, c = lane & 15;
    const int id = blockIdx.x;
    const int qt = 31 - (id >> 5);             // heavy first
    const int bh = id & 31;
    const int b = bh >> 4, h = bh & 15;

    const bf16_t* qbase = qg  + (size_t)bh * 2048 * 64;
    const bf16_t* kbase = kg  + (size_t)bh * 2048 * 64;
    const bf16_t* vbase = vtg + (size_t)bh * 64 * 2048;
    float* obase = out + (size_t)b * 2048 * 1024 + h * 64;

    const int srow = lane >> 3;                 // row within 8-row chunk
    const int scol = ((lane & 7) ^ srow) * 8;   // pre-swizzled source column (bf16 units)

    const int q0 = qt * 64;
    const int nt = qt + 1;

    // Q fragments (wave owns q-rows q0+w*16 .. +15), pre-scaled into log2 domain
    bf16x8 qf[2];
    #pragma unroll
    for (int kf = 0; kf < 2; ++kf) {
        bf16x8 v = *(const bf16x8*)(qbase + (size_t)(q0 + w*16 + c) * 64 + kf*32 + g*8);
        #pragma unroll
        for (int e = 0; e < 8; ++e) qf[kf][e] = (bf16_t)((float)v[e] * QK_SCALE);
    }

    f32x4 oacc[4] = {};
    float mrun = -INFINITY, lrun = 0.0f;

    // per wave per tile: 4 gload_lds16 (2 K-chunks + 2 V-chunks of 8 rows each)
    #define ATTN_STAGE(buf, kt)                                                          \
        do {                                                                             \
            char* Kb_ = smem + (buf) * 16384;                                            \
            _Pragma("unroll")                                                            \
            for (int j = 0; j < 2; ++j) {                                                \
                gload_lds16(kbase + (size_t)((kt)*64 + w*16 + j*8 + srow) * 64 + scol,   \
                            Kb_ + (w*16 + j*8) * 128);                                   \
                gload_lds16(vbase + (size_t)(w*16 + j*8 + srow) * 2048 + (kt)*64 + scol, \
                            Kb_ + 8192 + (w*16 + j*8) * 128);                            \
            }                                                                            \
        } while (0)

    ATTN_STAGE(0, 0);
    if (nt > 1) ATTN_STAGE(1, 1);
    int cur = 0;

    for (int kt = 0; kt < nt; ++kt) {
        if (kt == nt - 1) asm volatile("s_waitcnt vmcnt(0)" ::: "memory");
        else              asm volatile("s_waitcnt vmcnt(4)" ::: "memory");
        __builtin_amdgcn_s_barrier();
        asm volatile("" ::: "memory");
        if (kt + 2 < nt) {
            int b2 = cur + 2; if (b2 >= 3) b2 -= 3;
            ATTN_STAGE(b2, kt + 2);
        }
        const char* Ks = smem + cur * 16384;
        const char* Vs = Ks + 8192;

        // S^T tile: mfma(A=K rows, B=Q rows) -> lane(g,c) holds
        // S[q = q0+w*16+c][k = kt*64 + ni*16 + g*4 + e], already in log2 domain.
        f32x4 sacc[4];
        #pragma unroll
        for (int ni = 0; ni < 4; ++ni) {
            int krow = ni*16 + c;
            bf16x8 k0 = *(const bf16x8*)(Ks + krow*128 + ((     g*16) ^ ((c & 7) << 4)));
            bf16x8 k1 = *(const bf16x8*)(Ks + krow*128 + ((64 + g*16) ^ ((c & 7) << 4)));
            f32x4 s0 = {0.f, 0.f, 0.f, 0.f};
            s0 = __builtin_amdgcn_mfma_f32_16x16x32_bf16(k0, qf[0], s0, 0, 0, 0);
            s0 = __builtin_amdgcn_mfma_f32_16x16x32_bf16(k1, qf[1], s0, 0, 0, 0);
            sacc[ni] = s0;
        }

        if (kt == nt - 1) {   // diagonal tile: causal mask (k > q -> -inf)
            const int qloc = w*16 + c;
            #pragma unroll
            for (int ni = 0; ni < 4; ++ni)
                #pragma unroll
                for (int e = 0; e < 4; ++e)
                    if (ni*16 + g*4 + e > qloc) sacc[ni][e] = -INFINITY;
        }

        // lane-local row max over 16 + 2 cross-group shuffles
        float pmax;
        {
            float a0 = fmaxf(fmaxf(sacc[0][0], sacc[0][1]), fmaxf(sacc[0][2], sacc[0][3]));
            float a1 = fmaxf(fmaxf(sacc[1][0], sacc[1][1]), fmaxf(sacc[1][2], sacc[1][3]));
            float a2 = fmaxf(fmaxf(sacc[2][0], sacc[2][1]), fmaxf(sacc[2][2], sacc[2][3]));
            float a3 = fmaxf(fmaxf(sacc[3][0], sacc[3][1]), fmaxf(sacc[3][2], sacc[3][3]));
            pmax = fmaxf(fmaxf(a0, a1), fmaxf(a2, a3));
            pmax = fmaxf(pmax, __shfl_xor(pmax, 16));
            pmax = fmaxf(pmax, __shfl_xor(pmax, 32));
        }

        // defer-max: only rescale when some row grew by > 8 (log2 units; P <= 256)
        if (__any(pmax > mrun + 8.0f)) {
            float mnew = fmaxf(mrun, pmax);
            float sc = exp2f(mrun - mnew);        // exp2(-inf)=0 handles first tile
            float s0_ = __shfl(sc, g*4 + 0);      // redistribute to oacc row layout
            float s1_ = __shfl(sc, g*4 + 1);
            float s2_ = __shfl(sc, g*4 + 2);
            float s3_ = __shfl(sc, g*4 + 3);
            #pragma unroll
            for (int db = 0; db < 4; ++db) {
                oacc[db][0] *= s0_; oacc[db][1] *= s1_;
                oacc[db][2] *= s2_; oacc[db][3] *= s3_;
            }
            lrun *= sc;
            mrun = mnew;
        }

        // P = exp2(S - m), packed straight into MFMA A-fragments
        float psum = 0.f;
        bf16x8 palo, pahi;
        #pragma unroll
        for (int ni = 0; ni < 4; ++ni)
            #pragma unroll
            for (int e = 0; e < 4; ++e) {
                float pv = exp2f(sacc[ni][e] - mrun);
                psum += pv;
                if (ni < 2) palo[(ni & 1)*4 + e] = (bf16_t)pv;
                else        pahi[(ni & 1)*4 + e] = (bf16_t)pv;
            }
        psum += __shfl_xor(psum, 16);
        psum += __shfl_xor(psum, 32);
        lrun += psum;

        // O += P V : V fragments assembled with the same ni-concatenated k-mapping
        #pragma unroll
        for (int db = 0; db < 4; ++db) {
            int vrow = db*16 + c;
            bf16x4 v0 = *(const bf16x4*)(Vs + vrow*128 + ((     g*8) ^ ((c & 7) << 4)));
            bf16x4 v1 = *(const bf16x4*)(Vs + vrow*128 + ((32 + g*8) ^ ((c & 7) << 4)));
            bf16x4 v2 = *(const bf16x4*)(Vs + vrow*128 + ((64 + g*8) ^ ((c & 7) << 4)));
            bf16x4 v3 = *(const bf16x4*)(Vs + vrow*128 + ((96 + g*8) ^ ((c & 7) << 4)));
            bf16x8 vlo = __builtin_shufflevector(v0, v1, 0, 1, 2, 3, 4, 5, 6, 7);
            bf16x8 vhi = __builtin_shufflevector(v2, v3, 0, 1, 2, 3, 4, 5, 6, 7);
            oacc[db] = __builtin_amdgcn_mfma_f32_16x16x32_bf16(palo, vlo, oacc[db], 0, 0, 0);
            oacc[db] = __builtin_amdgcn_mfma_f32_16x16x32_bf16(pahi, vhi, oacc[db], 0, 0, 0);
        }

        cur = (cur == 2) ? 0 : cur + 1;
    }

    // epilogue: pull each oacc row's l, normalize, fp32 store [b][t][h*64+d]
    float inv[4];
    #pragma unroll
    for (int e = 0; e < 4; ++e) inv[e] = 1.0f / __shfl(lrun, g*4 + e);
    #pragma unroll
    for (int e = 0; e < 4; ++e) {
        size_t trow = (size_t)(q0 + w*16 + g*4 + e);
        #pragma unroll
        for (int db = 0; db < 4; ++db)
            obase[trow * 1024 + db*16 + c] = oacc[db][e] * inv[e];
    }
    #undef ATTN_STAGE
}

extern "C" void kernel_launch(void* const* d_in, const int* in_sizes, int n_in,
                              void* d_out, int out_size, void* d_ws, size_t ws_size,
                              hipStream_t stream) {
    const float* emb = (const float*)d_in[0];
    const float* wq  = (const float*)d_in[1];
    const float* wk  = (const float*)d_in[2];
    const float* wv  = (const float*)d_in[3];
    float* out = (float*)d_out;

    char* ws = (char*)d_ws;
    bf16_t* embb = (bf16_t*)ws;                          // 8 MB  [4096][1024]
    bf16_t* wcat = (bf16_t*)(ws + (size_t) 8*1024*1024); // 6 MB  [3072][1024]
    bf16_t* qb   = (bf16_t*)(ws + (size_t)14*1024*1024); // 8 MB  [BH][T][D]
    bf16_t* kb   = (bf16_t*)(ws + (size_t)22*1024*1024); // 8 MB  [BH][T][D]
    bf16_t* vtb  = (bf16_t*)(ws + (size_t)30*1024*1024); // 8 MB  [BH][D][T]

    convert_kernel<<<3584, 256, 0, stream>>>(emb, wq, wk, wv, embb, wcat);
    proj_kernel<<<768, 256, 0, stream>>>(embb, wcat, qb, kb, vtb);
    attn_kernel<<<1024, 256, 0, stream>>>(qb, kb, vtb, out);
}

// Round 5
// 151.268 us; speedup vs baseline: 1.3948x; 1.0210x over previous
//
#include <hip/hip_runtime.h>
#include <hip/hip_bf16.h>
#include <stdint.h>

typedef __bf16 bf16_t;
typedef __bf16 bf16x4 __attribute__((ext_vector_type(4)));
typedef __bf16 bf16x8 __attribute__((ext_vector_type(8)));
typedef float  f32x4  __attribute__((ext_vector_type(4)));

#define QK_SCALE 0.1803368801111204f   /* 0.125 * log2(e): softmax in log2 domain */

// async global->LDS, 16B per lane. LDS dest must be wave-uniform base (+lane*16 by HW).
__device__ __forceinline__ void gload_lds16(const void* g, void* l) {
    __builtin_amdgcn_global_load_lds(
        (__attribute__((address_space(1))) unsigned int*)(uintptr_t)g,
        (__attribute__((address_space(3))) unsigned int*)(uint32_t)(uintptr_t)l,
        16, 0, 0);
}

// ---------------- kernel 1: fp32 -> bf16 conversion / weight packing ----------
__global__ __launch_bounds__(256) void convert_kernel(
    const float* __restrict__ emb, const float* __restrict__ wq,
    const float* __restrict__ wk,  const float* __restrict__ wv,
    bf16_t* __restrict__ embb, bf16_t* __restrict__ wcat)
{
    size_t base = ((size_t)blockIdx.x * 256 + threadIdx.x) * 8;
    const float* src;
    bf16_t* dst;
    if (base < (size_t)4194304) { src = emb + base; dst = embb + base; }
    else {
        size_t r = base - 4194304;
        int wsel = (int)(r >> 20);
        size_t off = r & 1048575;
        src = (wsel == 0 ? wq : (wsel == 1 ? wk : wv)) + off;
        dst = wcat + r;
    }
    float4 a  = *(const float4*)src;
    float4 c2 = *(const float4*)(src + 4);
    bf16x8 o;
    o[0]=(bf16_t)a.x;  o[1]=(bf16_t)a.y;  o[2]=(bf16_t)a.z;  o[3]=(bf16_t)a.w;
    o[4]=(bf16_t)c2.x; o[5]=(bf16_t)c2.y; o[6]=(bf16_t)c2.z; o[7]=(bf16_t)c2.w;
    *(bf16x8*)dst = o;
}

// ---------------- kernel 2: QKV projection (NT GEMM, 3-buf counted-vmcnt) -----
// C[4096][3072] = A[4096][1024] * Wc[3072][1024]^T
// q,k: [B][H][T][D] bf16 ; vt: [B][H][D][T'] bf16 with t' = sigma(t) per 64-block,
// sigma(ni*16+g*4+e) = g*16 + (ni>>1)*8 + (ni&1)*4 + e  (PV-fragment-native order)
__global__ __launch_bounds__(256, 3) void proj_kernel(
    const bf16_t* __restrict__ A, const bf16_t* __restrict__ Wc,
    bf16_t* __restrict__ qo, bf16_t* __restrict__ ko, bf16_t* __restrict__ vto)
{
    __shared__ __align__(128) char smem[49152];
    // buf i at smem+i*16384: As [128 rows][64B] slot-swizzled, Bs at +8192

    const int tid  = threadIdx.x;
    const int w    = tid >> 6, lane = tid & 63;
    const int wr   = w >> 1,  wc2  = w & 1;
    const int g    = lane >> 4, c = lane & 15;
    const int bm   = blockIdx.x & 31, bn = blockIdx.x >> 5;
    const int m0   = bm * 128, n0 = bn * 128;

    f32x4 acc[4][4] = {};

    const int arow = lane >> 2;                              // 4 lanes per 64B row
    const int acol = (((lane & 3) ^ ((lane >> 3) & 3))) * 8; // pre-swizzled source slot

    #define PROJ_STAGE(buf, kt)                                                        \
        do {                                                                           \
            char* As_ = smem + (buf) * 16384;                                          \
            char* Bs_ = As_ + 8192;                                                    \
            _Pragma("unroll")                                                          \
            for (int p = 0; p < 2; ++p) {                                              \
                gload_lds16(A  + (size_t)(m0 + p*64 + w*16 + arow) * 1024 + (kt)*32 + acol, \
                            As_ + (p*64 + w*16) * 64);                                 \
                gload_lds16(Wc + (size_t)(n0 + p*64 + w*16 + arow) * 1024 + (kt)*32 + acol, \
                            Bs_ + (p*64 + w*16) * 64);                                 \
            }                                                                          \
        } while (0)

    PROJ_STAGE(0, 0);
    PROJ_STAGE(1, 1);
    int cur = 0;
    for (int kt = 0; kt < 32; ++kt) {
        if (kt == 31) asm volatile("s_waitcnt vmcnt(0)" ::: "memory");
        else          asm volatile("s_waitcnt vmcnt(4)" ::: "memory");
        __builtin_amdgcn_s_barrier();
        asm volatile("" ::: "memory");
        if (kt + 2 < 32) {
            int b2 = cur + 2; if (b2 >= 3) b2 -= 3;
            PROJ_STAGE(b2, kt + 2);
        }
        const char* As = smem + cur * 16384;
        const char* Bs = As + 8192;
        const int sw = (c >> 1) & 3;  // row-slot swizzle key
        bf16x8 af[4], bf[4];
        #pragma unroll
        for (int i = 0; i < 4; ++i) {
            af[i] = *(const bf16x8*)(As + (wr*64  + i*16 + c) * 64 + ((g ^ sw) << 4));
            bf[i] = *(const bf16x8*)(Bs + (wc2*64 + i*16 + c) * 64 + ((g ^ sw) << 4));
        }
        __builtin_amdgcn_s_setprio(1);
        #pragma unroll
        for (int i = 0; i < 4; ++i)
            #pragma unroll
            for (int j = 0; j < 4; ++j)
                acc[i][j] = __builtin_amdgcn_mfma_f32_16x16x32_bf16(af[i], bf[j], acc[i][j], 0, 0, 0);
        __builtin_amdgcn_s_setprio(0);
        cur = (cur == 2) ? 0 : cur + 1;
    }
    __syncthreads();   // all waves done with LDS bufs before epilogue reuses smem

    const int b  = m0 >> 11;
    const int t0 = m0 & 2047;

    if (n0 < 2048) {
        // q or k: [t][n] orientation in LDS, 16B-row stores of [b][h][t][d]
        bf16_t* dst = (n0 < 1024) ? qo : ko;
        const int nl0 = n0 & 1023;
        #pragma unroll
        for (int i = 0; i < 4; ++i)
            #pragma unroll
            for (int j = 0; j < 4; ++j) {
                int dl = wc2*64 + j*16 + c;
                #pragma unroll
                for (int e = 0; e < 4; ++e) {
                    int tl = wr*64 + i*16 + g*4 + e;
                    *(bf16_t*)(smem + ((tl*256 + dl*2) ^ ((tl & 7) << 4))) = (bf16_t)acc[i][j][e];
                }
            }
        __syncthreads();
        #pragma unroll
        for (int it = 0; it < 8; ++it) {
            int chunk = it * 256 + tid;          // 2048 x 16B chunks
            int tl = chunk >> 4;
            int ce = (chunk & 15) * 8;
            bf16x8 val = *(const bf16x8*)(smem + ((tl*256 + ce*2) ^ ((tl & 7) << 4)));
            int nn = nl0 + ce;
            int hh = nn >> 6, dd = nn & 63;
            *(bf16x8*)(dst + ((size_t)(b*16 + hh) * 2048 + (t0 + tl)) * 64 + dd) = val;
        }
    } else {
        // v: [n][t] orientation in LDS, sigma-permuted 16B-row stores of [b][h][d][t']
        #pragma unroll
        for (int i = 0; i < 4; ++i)
            #pragma unroll
            for (int j = 0; j < 4; ++j) {
                int dl = wc2*64 + j*16 + c;
                #pragma unroll
                for (int e = 0; e < 4; ++e) {
                    int tl = wr*64 + i*16 + g*4 + e;
                    *(bf16_t*)(smem + ((dl*256 + tl*2) ^ ((dl & 7) << 4))) = (bf16_t)acc[i][j][e];
                }
            }
        __syncthreads();
        const int nvbase = n0 - 2048;
        #pragma unroll
        for (int it = 0; it < 8; ++it) {
            int chunk = it * 256 + tid;
            int dl = chunk >> 4;
            int tl = (chunk & 15) * 8;           // permuted-local t' (0..120, step 8)
            int B64 = tl >> 6;
            int r   = tl & 63;                   // = G*16 + N8*8
            int t_a = B64*64 + ((r >> 3) & 1) * 32 + (r >> 4) * 4;  // sigma^-1 run start
            bf16x4 lo = *(const bf16x4*)(smem + ((dl*256 + t_a*2)      ^ ((dl & 7) << 4)));
            bf16x4 hi = *(const bf16x4*)(smem + ((dl*256 + (t_a+16)*2) ^ ((dl & 7) << 4)));
            bf16x8 val = __builtin_shufflevector(lo, hi, 0, 1, 2, 3, 4, 5, 6, 7);
            int nv = nvbase + dl;
            int hh = nv >> 6, dd = nv & 63;
            *(bf16x8*)(vto + (size_t)((b*16 + hh)*64 + dd) * 2048 + t0 + tl) = val;
        }
    }
    #undef PROJ_STAGE
}

// ---------------- kernel 3: causal flash attention ----------------------------
// Swapped QK^T (mfma(K,Q)) -> lane-local softmax rows; P in registers feeds PV
// via ni-block k-bijection; V stored sigma-permuted so PV reads are ds_read_b128.
// 8 waves x 16 q-rows (QBLK=128), KVBLK=64, 3-buf, counted vmcnt(2).
// grid 512: j=id>>5 -> qt = j<8 ? 15-j : j-8 (pair-balanced), bh = id&31.
__global__ __launch_bounds__(512, 4) void attn_kernel(
    const bf16_t* __restrict__ qg, const bf16_t* __restrict__ kg,
    const bf16_t* __restrict__ vtg, float* __restrict__ out)
{
    __shared__ __align__(128) char smem[49152];
    // buf i at smem+i*16384: Ks [64 t][64 d] swz (8KB), Vs [64 d][64 t'] swz (8KB)

    const int tid = threadIdx.x;
    const int w = tid >> 6, lane = tid & 63;   // 8 waves
    const int g = lane >> 4, c = lane & 15;
    const int id = blockIdx.x;
    const int j = id >> 5;
    const int qt = (j < 8) ? (15 - j) : (j - 8);   // pair-balanced schedule
    const int bh = id & 31;
    const int b = bh >> 4, h = bh & 15;

    const bf16_t* qbase = qg  + (size_t)bh * 2048 * 64;
    const bf16_t* kbase = kg  + (size_t)bh * 2048 * 64;
    const bf16_t* vbase = vtg + (size_t)bh * 64 * 2048;
    float* obase = out + (size_t)b * 2048 * 1024 + h * 64;

    const int srow = lane >> 3;                 // row within 8-row chunk
    const int scol = ((lane & 7) ^ srow) * 8;   // pre-swizzled source column (bf16)

    const int q0 = qt * 128;
    const int nt = 2 * qt + 2;

    // Q fragments first (their vmcnt drains via the converts below, keeping the
    // staging vmcnt counting clean). Wave owns q-rows q0 + w*16 .. +15.
    bf16x8 qf[2];
    #pragma unroll
    for (int kf = 0; kf < 2; ++kf) {
        bf16x8 v = *(const bf16x8*)(qbase + (size_t)(q0 + w*16 + c) * 64 + kf*32 + g*8);
        #pragma unroll
        for (int e = 0; e < 8; ++e) qf[kf][e] = (bf16_t)((float)v[e] * QK_SCALE);
    }

    f32x4 oacc[4] = {};
    float mrun = -INFINITY, lrun = 0.0f;

    // per wave per tile: 2 gload_lds16 (1 K-chunk + 1 V-chunk of 8 rows each)
    #define ATTN_STAGE(buf, kt)                                                        \
        do {                                                                           \
            char* Kb_ = smem + (buf) * 16384;                                          \
            gload_lds16(kbase + (size_t)((kt)*64 + w*8 + srow) * 64 + scol,            \
                        Kb_ + w*1024);                                                 \
            gload_lds16(vbase + (size_t)(w*8 + srow) * 2048 + (kt)*64 + scol,          \
                        Kb_ + 8192 + w*1024);                                          \
        } while (0)

    ATTN_STAGE(0, 0);
    ATTN_STAGE(1, 1);   // nt >= 2 always
    int cur = 0;

    for (int kt = 0; kt < nt; ++kt) {
        if (kt == nt - 1) asm volatile("s_waitcnt vmcnt(0)" ::: "memory");
        else              asm volatile("s_waitcnt vmcnt(2)" ::: "memory");
        __builtin_amdgcn_s_barrier();
        asm volatile("" ::: "memory");
        if (kt + 2 < nt) {
            int b2 = cur + 2; if (b2 >= 3) b2 -= 3;
            ATTN_STAGE(b2, kt + 2);
        }
        const char* Ks = smem + cur * 16384;
        const char* Vs = Ks + 8192;

        // S^T tile: mfma(A=K rows, B=Q rows) -> lane(g,c) holds
        // S[q = q0+w*16+c][k = kt*64 + ni*16 + g*4 + e], in log2 domain.
        f32x4 sacc[4];
        __builtin_amdgcn_s_setprio(1);
        #pragma unroll
        for (int ni = 0; ni < 4; ++ni) {
            int krow = ni*16 + c;
            bf16x8 k0 = *(const bf16x8*)(Ks + krow*128 + ((     g*16) ^ ((c & 7) << 4)));
            bf16x8 k1 = *(const bf16x8*)(Ks + krow*128 + ((64 + g*16) ^ ((c & 7) << 4)));
            f32x4 s0 = {0.f, 0.f, 0.f, 0.f};
            s0 = __builtin_amdgcn_mfma_f32_16x16x32_bf16(k0, qf[0], s0, 0, 0, 0);
            s0 = __builtin_amdgcn_mfma_f32_16x16x32_bf16(k1, qf[1], s0, 0, 0, 0);
            sacc[ni] = s0;
        }
        __builtin_amdgcn_s_setprio(0);

        if (kt >= nt - 2) {   // last two tiles may cross the diagonal
            const int qloc = w*16 + c;
            const int koff = (kt - (nt - 2)) * 64;
            #pragma unroll
            for (int ni = 0; ni < 4; ++ni)
                #pragma unroll
                for (int e = 0; e < 4; ++e)
                    if (koff + ni*16 + g*4 + e > qloc) sacc[ni][e] = -INFINITY;
        }

        // row max: max3-shaped in-lane tree + 2 cross-group shuffles
        float pmax;
        {
            float t0_ = fmaxf(fmaxf(sacc[0][0], sacc[0][1]), sacc[0][2]);
            float t1_ = fmaxf(fmaxf(sacc[0][3], sacc[1][0]), sacc[1][1]);
            float t2_ = fmaxf(fmaxf(sacc[1][2], sacc[1][3]), sacc[2][0]);
            float t3_ = fmaxf(fmaxf(sacc[2][1], sacc[2][2]), sacc[2][3]);
            float t4_ = fmaxf(fmaxf(sacc[3][0], sacc[3][1]), sacc[3][2]);
            float u_  = fmaxf(fmaxf(t0_, t1_), t2_);
            float v_  = fmaxf(fmaxf(t3_, t4_), sacc[3][3]);
            pmax = fmaxf(u_, v_);
            pmax = fmaxf(pmax, __shfl_xor(pmax, 16));
            pmax = fmaxf(pmax, __shfl_xor(pmax, 32));
        }

        // defer-max: rescale only when some row grew by > 8 (log2 units; P <= 256)
        if (__any(pmax > mrun + 8.0f)) {
            float mnew = fmaxf(mrun, pmax);
            float sc = exp2f(mrun - mnew);        // exp2(-inf)=0 handles first tile
            float s0_ = __shfl(sc, g*4 + 0);      // redistribute to oacc row layout
            float s1_ = __shfl(sc, g*4 + 1);
            float s2_ = __shfl(sc, g*4 + 2);
            float s3_ = __shfl(sc, g*4 + 3);
            #pragma unroll
            for (int db = 0; db < 4; ++db) {
                oacc[db][0] *= s0_; oacc[db][1] *= s1_;
                oacc[db][2] *= s2_; oacc[db][3] *= s3_;
            }
            lrun *= sc;
            mrun = mnew;
        }

        // P = exp2(S - m), packed straight into MFMA A-fragments
        float psum = 0.f;
        bf16x8 palo, pahi;
        #pragma unroll
        for (int ni = 0; ni < 4; ++ni)
            #pragma unroll
            for (int e = 0; e < 4; ++e) {
                float pv = exp2f(sacc[ni][e] - mrun);
                psum += pv;
                if (ni < 2) palo[(ni & 1)*4 + e] = (bf16_t)pv;
                else        pahi[(ni & 1)*4 + e] = (bf16_t)pv;
            }

        // O += P V : sigma-stored V -> two b128 reads per db, fragment-native order
        __builtin_amdgcn_s_setprio(1);
        #pragma unroll
        for (int db = 0; db < 4; ++db) {
            int vrow = db*16 + c;
            bf16x8 vlo = *(const bf16x8*)(Vs + vrow*128 + ((g*32     ) ^ ((c & 7) << 4)));
            bf16x8 vhi = *(const bf16x8*)(Vs + vrow*128 + ((g*32 + 16) ^ ((c & 7) << 4)));
            oacc[db] = __builtin_amdgcn_mfma_f32_16x16x32_bf16(palo, vlo, oacc[db], 0, 0, 0);
            oacc[db] = __builtin_amdgcn_mfma_f32_16x16x32_bf16(pahi, vhi, oacc[db], 0, 0, 0);
        }
        __builtin_amdgcn_s_setprio(0);

        // finish l off the critical path
        psum += __shfl_xor(psum, 16);
        psum += __shfl_xor(psum, 32);
        lrun += psum;

        cur = (cur == 2) ? 0 : cur + 1;
    }

    // epilogue: pull each oacc row's l, normalize, fp32 store [b][t][h*64+d]
    float inv[4];
    #pragma unroll
    for (int e = 0; e < 4; ++e) inv[e] = 1.0f / __shfl(lrun, g*4 + e);
    #pragma unroll
    for (int e = 0; e < 4; ++e) {
        size_t trow = (size_t)(q0 + w*16 + g*4 + e);
        #pragma unroll
        for (int db = 0; db < 4; ++db)
            obase[trow * 1024 + db*16 + c] = oacc[db][e] * inv[e];
    }
    #undef ATTN_STAGE
}

extern "C" void kernel_launch(void* const* d_in, const int* in_sizes, int n_in,
                              void* d_out, int out_size, void* d_ws, size_t ws_size,
                              hipStream_t stream) {
    const float* emb = (const float*)d_in[0];
    const float* wq  = (const float*)d_in[1];
    const float* wk  = (const float*)d_in[2];
    const float* wv  = (const float*)d_in[3];
    float* out = (float*)d_out;

    char* ws = (char*)d_ws;
    bf16_t* embb = (bf16_t*)ws;                          // 8 MB  [4096][1024]
    bf16_t* wcat = (bf16_t*)(ws + (size_t) 8*1024*1024); // 6 MB  [3072][1024]
    bf16_t* qb   = (bf16_t*)(ws + (size_t)14*1024*1024); // 8 MB  [BH][T][D]
    bf16_t* kb   = (bf16_t*)(ws + (size_t)22*1024*1024); // 8 MB  [BH][T][D]
    bf16_t* vtb  = (bf16_t*)(ws + (size_t)30*1024*1024); // 8 MB  [BH][D][T'] sigma-permuted

    convert_kernel<<<3584, 256, 0, stream>>>(emb, wq, wk, wv, embb, wcat);
    proj_kernel<<<768, 256, 0, stream>>>(embb, wcat, qb, kb, vtb);
    attn_kernel<<<512, 512, 0, stream>>>(qb, kb, vtb, out);
}

// Round 6
// 150.898 us; speedup vs baseline: 1.3983x; 1.0025x over previous
//
#include <hip/hip_runtime.h>
#include <hip/hip_bf16.h>
#include <stdint.h>

typedef __bf16 bf16_t;
typedef __bf16 bf16x4 __attribute__((ext_vector_type(4)));
typedef __bf16 bf16x8 __attribute__((ext_vector_type(8)));
typedef float  f32x4  __attribute__((ext_vector_type(4)));

#define QK_SCALE 0.1803368801111204f   /* 0.125 * log2(e): softmax in log2 domain */

// async global->LDS, 16B per lane. LDS dest must be wave-uniform base (+lane*16 by HW).
__device__ __forceinline__ void gload_lds16(const void* g, void* l) {
    __builtin_amdgcn_global_load_lds(
        (__attribute__((address_space(1))) unsigned int*)(uintptr_t)g,
        (__attribute__((address_space(3))) unsigned int*)(uint32_t)(uintptr_t)l,
        16, 0, 0);
}

// ---------------- kernel 1: fp32 -> bf16 conversion / weight packing ----------
__global__ __launch_bounds__(256) void convert_kernel(
    const float* __restrict__ emb, const float* __restrict__ wq,
    const float* __restrict__ wk,  const float* __restrict__ wv,
    bf16_t* __restrict__ embb, bf16_t* __restrict__ wcat)
{
    size_t base = ((size_t)blockIdx.x * 256 + threadIdx.x) * 8;
    const float* src;
    bf16_t* dst;
    if (base < (size_t)4194304) { src = emb + base; dst = embb + base; }
    else {
        size_t r = base - 4194304;
        int wsel = (int)(r >> 20);
        size_t off = r & 1048575;
        src = (wsel == 0 ? wq : (wsel == 1 ? wk : wv)) + off;
        dst = wcat + r;
    }
    float4 a  = *(const float4*)src;
    float4 c2 = *(const float4*)(src + 4);
    bf16x8 o;
    o[0]=(bf16_t)a.x;  o[1]=(bf16_t)a.y;  o[2]=(bf16_t)a.z;  o[3]=(bf16_t)a.w;
    o[4]=(bf16_t)c2.x; o[5]=(bf16_t)c2.y; o[6]=(bf16_t)c2.z; o[7]=(bf16_t)c2.w;
    *(bf16x8*)dst = o;
}

// ---------------- kernel 2: QKV projection (NT GEMM, 3-buf counted-vmcnt) -----
// C[4096][3072] = A[4096][1024] * Wc[3072][1024]^T
// q,k: [B][H][T][D] bf16 ; vt: [B][H][D][T'] bf16 with t' = sigma(t) per 64-block,
// sigma(ni*16+g*4+e) = g*16 + (ni>>1)*8 + (ni&1)*4 + e  (PV-fragment-native order)
__global__ __launch_bounds__(256, 3) void proj_kernel(
    const bf16_t* __restrict__ A, const bf16_t* __restrict__ Wc,
    bf16_t* __restrict__ qo, bf16_t* __restrict__ ko, bf16_t* __restrict__ vto)
{
    __shared__ __align__(128) char smem[49152];
    // buf i at smem+i*16384: As [128 rows][64B] slot-swizzled, Bs at +8192

    const int tid  = threadIdx.x;
    const int w    = tid >> 6, lane = tid & 63;
    const int wr   = w >> 1,  wc2  = w & 1;
    const int g    = lane >> 4, c = lane & 15;
    const int bm   = blockIdx.x & 31, bn = blockIdx.x >> 5;
    const int m0   = bm * 128, n0 = bn * 128;

    f32x4 acc[4][4] = {};

    const int arow = lane >> 2;                              // 4 lanes per 64B row
    const int acol = (((lane & 3) ^ ((lane >> 3) & 3))) * 8; // pre-swizzled source slot

    #define PROJ_STAGE(buf, kt)                                                        \
        do {                                                                           \
            char* As_ = smem + (buf) * 16384;                                          \
            char* Bs_ = As_ + 8192;                                                    \
            _Pragma("unroll")                                                          \
            for (int p = 0; p < 2; ++p) {                                              \
                gload_lds16(A  + (size_t)(m0 + p*64 + w*16 + arow) * 1024 + (kt)*32 + acol, \
                            As_ + (p*64 + w*16) * 64);                                 \
                gload_lds16(Wc + (size_t)(n0 + p*64 + w*16 + arow) * 1024 + (kt)*32 + acol, \
                            Bs_ + (p*64 + w*16) * 64);                                 \
            }                                                                          \
        } while (0)

    PROJ_STAGE(0, 0);
    PROJ_STAGE(1, 1);
    int cur = 0;
    for (int kt = 0; kt < 32; ++kt) {
        if (kt == 31) asm volatile("s_waitcnt vmcnt(0)" ::: "memory");
        else          asm volatile("s_waitcnt vmcnt(4)" ::: "memory");
        __builtin_amdgcn_s_barrier();
        asm volatile("" ::: "memory");
        if (kt + 2 < 32) {
            int b2 = cur + 2; if (b2 >= 3) b2 -= 3;
            PROJ_STAGE(b2, kt + 2);
        }
        const char* As = smem + cur * 16384;
        const char* Bs = As + 8192;
        const int sw = (c >> 1) & 3;  // row-slot swizzle key
        bf16x8 af[4], bf[4];
        #pragma unroll
        for (int i = 0; i < 4; ++i) {
            af[i] = *(const bf16x8*)(As + (wr*64  + i*16 + c) * 64 + ((g ^ sw) << 4));
            bf[i] = *(const bf16x8*)(Bs + (wc2*64 + i*16 + c) * 64 + ((g ^ sw) << 4));
        }
        __builtin_amdgcn_s_setprio(1);
        #pragma unroll
        for (int i = 0; i < 4; ++i)
            #pragma unroll
            for (int j = 0; j < 4; ++j)
                acc[i][j] = __builtin_amdgcn_mfma_f32_16x16x32_bf16(af[i], bf[j], acc[i][j], 0, 0, 0);
        __builtin_amdgcn_s_setprio(0);
        cur = (cur == 2) ? 0 : cur + 1;
    }
    __syncthreads();   // all waves done with LDS bufs before epilogue reuses smem

    const int b  = m0 >> 11;
    const int t0 = m0 & 2047;

    if (n0 < 2048) {
        // q or k: [t][n] orientation in LDS, 16B-row stores of [b][h][t][d]
        bf16_t* dst = (n0 < 1024) ? qo : ko;
        const int nl0 = n0 & 1023;
        #pragma unroll
        for (int i = 0; i < 4; ++i)
            #pragma unroll
            for (int j = 0; j < 4; ++j) {
                int dl = wc2*64 + j*16 + c;
                #pragma unroll
                for (int e = 0; e < 4; ++e) {
                    int tl = wr*64 + i*16 + g*4 + e;
                    *(bf16_t*)(smem + ((tl*256 + dl*2) ^ ((tl & 7) << 4))) = (bf16_t)acc[i][j][e];
                }
            }
        __syncthreads();
        #pragma unroll
        for (int it = 0; it < 8; ++it) {
            int chunk = it * 256 + tid;          // 2048 x 16B chunks
            int tl = chunk >> 4;
            int ce = (chunk & 15) * 8;
            bf16x8 val = *(const bf16x8*)(smem + ((tl*256 + ce*2) ^ ((tl & 7) << 4)));
            int nn = nl0 + ce;
            int hh = nn >> 6, dd = nn & 63;
            *(bf16x8*)(dst + ((size_t)(b*16 + hh) * 2048 + (t0 + tl)) * 64 + dd) = val;
        }
    } else {
        // v: [n][t] orientation in LDS, sigma-permuted 16B-row stores of [b][h][d][t']
        #pragma unroll
        for (int i = 0; i < 4; ++i)
            #pragma unroll
            for (int j = 0; j < 4; ++j) {
                int dl = wc2*64 + j*16 + c;
                #pragma unroll
                for (int e = 0; e < 4; ++e) {
                    int tl = wr*64 + i*16 + g*4 + e;
                    *(bf16_t*)(smem + ((dl*256 + tl*2) ^ ((dl & 7) << 4))) = (bf16_t)acc[i][j][e];
                }
            }
        __syncthreads();
        const int nvbase = n0 - 2048;
        #pragma unroll
        for (int it = 0; it < 8; ++it) {
            int chunk = it * 256 + tid;
            int dl = chunk >> 4;
            int tl = (chunk & 15) * 8;           // permuted-local t' (0..120, step 8)
            int B64 = tl >> 6;
            int r   = tl & 63;                   // = G*16 + N8*8
            int t_a = B64*64 + ((r >> 3) & 1) * 32 + (r >> 4) * 4;  // sigma^-1 run start
            bf16x4 lo = *(const bf16x4*)(smem + ((dl*256 + t_a*2)      ^ ((dl & 7) << 4)));
            bf16x4 hi = *(const bf16x4*)(smem + ((dl*256 + (t_a+16)*2) ^ ((dl & 7) << 4)));
            bf16x8 val = __builtin_shufflevector(lo, hi, 0, 1, 2, 3, 4, 5, 6, 7);
            int nv = nvbase + dl;
            int hh = nv >> 6, dd = nv & 63;
            *(bf16x8*)(vto + (size_t)((b*16 + hh)*64 + dd) * 2048 + t0 + tl) = val;
        }
    }
    #undef PROJ_STAGE
}

// ---------------- kernel 3: causal flash attention ----------------------------
// Swapped QK^T (mfma(K,Q)) -> lane-local softmax rows; P in registers feeds PV
// via ni-block k-bijection; V stored sigma-permuted so PV reads are ds_read_b128.
// 4 waves x 16 q-rows (QBLK=64), KVBLK=64, 3-buf, counted vmcnt(4).
// grid 1024, snake-balanced: every CU's 4 blocks sum to exactly 66 tiles;
// XCD x serves bh in {4x..4x+3} (K+V 2MB <= L2).
__global__ __launch_bounds__(256, 3) void attn_kernel(
    const bf16_t* __restrict__ qg, const bf16_t* __restrict__ kg,
    const bf16_t* __restrict__ vtg, float* __restrict__ out)
{
    __shared__ __align__(128) char smem[49152];
    // buf i at smem+i*16384: Ks [64 t][64 d] swz (8KB), Vs [64 d][64 t'] swz (8KB)

    const int tid = threadIdx.x;
    const int w = tid >> 6, lane = tid & 63;   // 4 waves
    const int g = lane >> 4, c = lane & 15;
    const int id = blockIdx.x;
    const int x  = id & 7;                     // XCD slot
    const int r  = id >> 3;                    // 0..127
    const int bh = x * 4 + (r & 3);
    const int sr = r >> 2;                     // 0..31
    const int s  = (sr & 24) | (((sr >> 3) & 1) ? (7 - (sr & 7)) : (sr & 7)); // snake
    const int b = bh >> 4, h = bh & 15;

    const bf16_t* qbase = qg  + (size_t)bh * 2048 * 64;
    const bf16_t* kbase = kg  + (size_t)bh * 2048 * 64;
    const bf16_t* vbase = vtg + (size_t)bh * 64 * 2048;
    float* obase = out + (size_t)b * 2048 * 1024 + h * 64;

    const int srow = lane >> 3;                 // row within 8-row chunk
    const int scol = ((lane & 7) ^ srow) * 8;   // pre-swizzled source column (bf16)

    const int nt = 32 - s;                      // heavy blocks first within XCD stream
    const int q0 = (nt - 1) * 64;

    // Q fragments (wave owns q-rows q0 + w*16 .. +15), pre-scaled into log2 domain
    bf16x8 qf[2];
    #pragma unroll
    for (int kf = 0; kf < 2; ++kf) {
        bf16x8 v = *(const bf16x8*)(qbase + (size_t)(q0 + w*16 + c) * 64 + kf*32 + g*8);
        #pragma unroll
        for (int e = 0; e < 8; ++e) qf[kf][e] = (bf16_t)((float)v[e] * QK_SCALE);
    }

    f32x4 oacc[4] = {};
    float mrun = -INFINITY, lrun = 0.0f;       // lrun: per-lane PARTIAL (reduced in epilogue)

    // per wave per tile: 4 gload_lds16 (2 K-chunks + 2 V-chunks of 8 rows each)
    #define ATTN_STAGE(buf, kt)                                                          \
        do {                                                                             \
            char* Kb_ = smem + (buf) * 16384;                                            \
            _Pragma("unroll")                                                            \
            for (int jj = 0; jj < 2; ++jj) {                                             \
                gload_lds16(kbase + (size_t)((kt)*64 + w*16 + jj*8 + srow) * 64 + scol,  \
                            Kb_ + (w*16 + jj*8) * 128);                                  \
                gload_lds16(vbase + (size_t)(w*16 + jj*8 + srow) * 2048 + (kt)*64 + scol,\
                            Kb_ + 8192 + (w*16 + jj*8) * 128);                           \
            }                                                                            \
        } while (0)

    ATTN_STAGE(0, 0);
    if (nt > 1) ATTN_STAGE(1, 1);
    int cur = 0;

    for (int kt = 0; kt < nt; ++kt) {
        if (kt == nt - 1) asm volatile("s_waitcnt vmcnt(0)" ::: "memory");
        else              asm volatile("s_waitcnt vmcnt(4)" ::: "memory");
        __builtin_amdgcn_s_barrier();
        asm volatile("" ::: "memory");
        if (kt + 2 < nt) {
            int b2 = cur + 2; if (b2 >= 3) b2 -= 3;
            ATTN_STAGE(b2, kt + 2);
        }
        const char* Ks = smem + cur * 16384;
        const char* Vs = Ks + 8192;

        // S^T tile: mfma(A=K rows, B=Q rows) -> lane(g,c) holds
        // S[q = q0+w*16+c][k = kt*64 + ni*16 + g*4 + e], in log2 domain.
        f32x4 sacc[4];
        __builtin_amdgcn_s_setprio(1);
        #pragma unroll
        for (int ni = 0; ni < 4; ++ni) {
            int krow = ni*16 + c;
            bf16x8 k0 = *(const bf16x8*)(Ks + krow*128 + ((     g*16) ^ ((c & 7) << 4)));
            bf16x8 k1 = *(const bf16x8*)(Ks + krow*128 + ((64 + g*16) ^ ((c & 7) << 4)));
            f32x4 s0 = {0.f, 0.f, 0.f, 0.f};
            s0 = __builtin_amdgcn_mfma_f32_16x16x32_bf16(k0, qf[0], s0, 0, 0, 0);
            s0 = __builtin_amdgcn_mfma_f32_16x16x32_bf16(k1, qf[1], s0, 0, 0, 0);
            sacc[ni] = s0;
        }
        __builtin_amdgcn_s_setprio(0);

        if (kt == nt - 1) {   // the single diagonal tile: causal mask (k > q -> -inf)
            const int qloc = w*16 + c;
            #pragma unroll
            for (int ni = 0; ni < 4; ++ni)
                #pragma unroll
                for (int e = 0; e < 4; ++e)
                    if (ni*16 + g*4 + e > qloc) sacc[ni][e] = -INFINITY;
        }

        // row max: max3-shaped in-lane tree + 2 cross-group shuffles
        float pmax;
        {
            float t0_ = fmaxf(fmaxf(sacc[0][0], sacc[0][1]), sacc[0][2]);
            float t1_ = fmaxf(fmaxf(sacc[0][3], sacc[1][0]), sacc[1][1]);
            float t2_ = fmaxf(fmaxf(sacc[1][2], sacc[1][3]), sacc[2][0]);
            float t3_ = fmaxf(fmaxf(sacc[2][1], sacc[2][2]), sacc[2][3]);
            float t4_ = fmaxf(fmaxf(sacc[3][0], sacc[3][1]), sacc[3][2]);
            float u_  = fmaxf(fmaxf(t0_, t1_), t2_);
            float v_  = fmaxf(fmaxf(t3_, t4_), sacc[3][3]);
            pmax = fmaxf(u_, v_);
            pmax = fmaxf(pmax, __shfl_xor(pmax, 16));
            pmax = fmaxf(pmax, __shfl_xor(pmax, 32));
        }

        // defer-max: rescale only when some row grew by > 8 (log2 units; P <= 256)
        if (__any(pmax > mrun + 8.0f)) {
            float mnew = fmaxf(mrun, pmax);
            float sc = exp2f(mrun - mnew);        // exp2(-inf)=0 handles first tile
            float s0_ = __shfl(sc, g*4 + 0);      // redistribute to oacc row layout
            float s1_ = __shfl(sc, g*4 + 1);
            float s2_ = __shfl(sc, g*4 + 2);
            float s3_ = __shfl(sc, g*4 + 3);
            #pragma unroll
            for (int db = 0; db < 4; ++db) {
                oacc[db][0] *= s0_; oacc[db][1] *= s1_;
                oacc[db][2] *= s2_; oacc[db][3] *= s3_;
            }
            lrun *= sc;                           // sc uniform across the row's g-lanes
            mrun = mnew;
        }

        // P = exp2(S - m), packed straight into MFMA A-fragments; lrun stays partial
        float psum = 0.f;
        bf16x8 palo, pahi;
        #pragma unroll
        for (int ni = 0; ni < 4; ++ni)
            #pragma unroll
            for (int e = 0; e < 4; ++e) {
                float pv = exp2f(sacc[ni][e] - mrun);
                psum += pv;
                if (ni < 2) palo[(ni & 1)*4 + e] = (bf16_t)pv;
                else        pahi[(ni & 1)*4 + e] = (bf16_t)pv;
            }
        lrun += psum;

        // O += P V : sigma-stored V -> two b128 reads per db, fragment-native order
        __builtin_amdgcn_s_setprio(1);
        #pragma unroll
        for (int db = 0; db < 4; ++db) {
            int vrow = db*16 + c;
            bf16x8 vlo = *(const bf16x8*)(Vs + vrow*128 + ((g*32     ) ^ ((c & 7) << 4)));
            bf16x8 vhi = *(const bf16x8*)(Vs + vrow*128 + ((g*32 + 16) ^ ((c & 7) << 4)));
            oacc[db] = __builtin_amdgcn_mfma_f32_16x16x32_bf16(palo, vlo, oacc[db], 0, 0, 0);
            oacc[db] = __builtin_amdgcn_mfma_f32_16x16x32_bf16(pahi, vhi, oacc[db], 0, 0, 0);
        }
        __builtin_amdgcn_s_setprio(0);

        cur = (cur == 2) ? 0 : cur + 1;
    }

    // epilogue: finish lrun row-reduction once, normalize, fp32 store [b][t][h*64+d]
    lrun += __shfl_xor(lrun, 16);
    lrun += __shfl_xor(lrun, 32);
    float inv[4];
    #pragma unroll
    for (int e = 0; e < 4; ++e) inv[e] = 1.0f / __shfl(lrun, g*4 + e);
    #pragma unroll
    for (int e = 0; e < 4; ++e) {
        size_t trow = (size_t)(q0 + w*16 + g*4 + e);
        #pragma unroll
        for (int db = 0; db < 4; ++db)
            obase[trow * 1024 + db*16 + c] = oacc[db][e] * inv[e];
    }
    #undef ATTN_STAGE
}

extern "C" void kernel_launch(void* const* d_in, const int* in_sizes, int n_in,
                              void* d_out, int out_size, void* d_ws, size_t ws_size,
                              hipStream_t stream) {
    const float* emb = (const float*)d_in[0];
    const float* wq  = (const float*)d_in[1];
    const float* wk  = (const float*)d_in[2];
    const float* wv  = (const float*)d_in[3];
    float* out = (float*)d_out;

    char* ws = (char*)d_ws;
    bf16_t* embb = (bf16_t*)ws;                          // 8 MB  [4096][1024]
    bf16_t* wcat = (bf16_t*)(ws + (size_t) 8*1024*1024); // 6 MB  [3072][1024]
    bf16_t* qb   = (bf16_t*)(ws + (size_t)14*1024*1024); // 8 MB  [BH][T][D]
    bf16_t* kb   = (bf16_t*)(ws + (size_t)22*1024*1024); // 8 MB  [BH][T][D]
    bf16_t* vtb  = (bf16_t*)(ws + (size_t)30*1024*1024); // 8 MB  [BH][D][T'] sigma-permuted

    convert_kernel<<<3584, 256, 0, stream>>>(emb, wq, wk, wv, embb, wcat);
    proj_kernel<<<768, 256, 0, stream>>>(embb, wcat, qb, kb, vtb);
    attn_kernel<<<1024, 256, 0, stream>>>(qb, kb, vtb, out);
}